// Round 3
// baseline (635.538 us; speedup 1.0000x reference)
//
#include <hip/hip_runtime.h>

// ---------------------------------------------------------------------------
// Model: xp = x @ W_ih^T + (b_ih + b_hh)   [bf16 MFMA GEMM, fp32 accumulate]
//        h_t = tanh(xp_t + h_{t-1} @ W_hh^T)   [fp32, latency-optimized scan]
//        out = LN(relu(relu(hT W1^T + b1) W2^T + b2))  [fused into RNN tail]
// ---------------------------------------------------------------------------

typedef __bf16 bf16x8 __attribute__((ext_vector_type(8)));
typedef float  f32x4  __attribute__((ext_vector_type(4)));

#define T_STEPS 512
#define I_DIM   2048
#define H_DIM   128
#define B_DIM   64
#define M_TOT   (B_DIM * T_STEPS)   // 32768

// RNE fp32 -> bf16 (inputs are finite; no NaN path needed)
__device__ __forceinline__ unsigned short f2bf(float f) {
    unsigned int u = __float_as_uint(f);
    u += 0x7FFFu + ((u >> 16) & 1u);
    return (unsigned short)(u >> 16);
}

// Pairwise (lane 2m <-> 2m+1) add via DPP quad_perm — VALU pipe, no LDS.
__device__ __forceinline__ float dpp_add_xor1(float x) {
    int t = __builtin_amdgcn_update_dpp(0, __float_as_int(x),
                                        0xB1 /*[1,0,3,2]*/, 0xF, 0xF, true);
    return x + __int_as_float(t);
}

// ---------------------------------------------------------------------------
// Kernel 1: xp[M,128] = x[M,2048] (bf16) @ W_ih[128,2048]^T (bf16) + bias
// BM=128, BN=128(=H), BK=64. 256 threads = 4 waves in 2x2, each wave 64x64.
// fp32 -> bf16 conversion fused into LDS staging (x read exactly once).
// Raw s_barrier + lgkmcnt(0) only (NOT __syncthreads): the k+1 global
// prefetch is never vmcnt-drained at the barrier; the compiler's register
// dataflow inserts the vmcnt wait right before store_tiles consumes ar/br.
// ---------------------------------------------------------------------------
#define BM  128
#define BK  64
#define LDK 72   // LDS row stride in bf16 elems (+8 pad -> 2-way-max bank alias)

__global__ __launch_bounds__(256) void gemm_xp(
    const float* __restrict__ x,      // [32768, 2048]
    const float* __restrict__ w,      // [128, 2048]
    const float* __restrict__ b_ih,   // [128]
    const float* __restrict__ b_hh,   // [128]
    float* __restrict__ xp)           // [32768, 128]
{
    __shared__ __align__(16) unsigned short As[BM * LDK];
    __shared__ __align__(16) unsigned short Bs[H_DIM * LDK];

    const int tid = threadIdx.x;
    const int m0  = blockIdx.x * BM;

    // staging map: per unroll step i (0..7), rows i*16 + r0, contiguous 256B/16 lanes
    const int r0 = tid >> 4;      // 0..15
    const int c4 = tid & 15;      // float4 column within 64-float row chunk

    const int lane = tid & 63;
    const int wave = tid >> 6;
    const int wm   = (wave >> 1) * 64;
    const int wn   = (wave & 1) * 64;
    const int l16  = lane & 15;
    const int quad = lane >> 4;

    f32x4 acc[4][4] = {};

    float4 ar[8], br[8];

    auto load_tiles = [&](int k0) {
        #pragma unroll
        for (int i = 0; i < 8; ++i)
            ar[i] = *(const float4*)(x + (size_t)(m0 + i * 16 + r0) * I_DIM + k0 + c4 * 4);
        #pragma unroll
        for (int i = 0; i < 8; ++i)
            br[i] = *(const float4*)(w + (size_t)(i * 16 + r0) * I_DIM + k0 + c4 * 4);
    };

    auto store_tiles = [&]() {
        #pragma unroll
        for (int i = 0; i < 8; ++i) {
            ushort4 v;
            v.x = f2bf(ar[i].x); v.y = f2bf(ar[i].y);
            v.z = f2bf(ar[i].z); v.w = f2bf(ar[i].w);
            *(ushort4*)(As + (i * 16 + r0) * LDK + c4 * 4) = v;
        }
        #pragma unroll
        for (int i = 0; i < 8; ++i) {
            ushort4 v;
            v.x = f2bf(br[i].x); v.y = f2bf(br[i].y);
            v.z = f2bf(br[i].z); v.w = f2bf(br[i].w);
            *(ushort4*)(Bs + (i * 16 + r0) * LDK + c4 * 4) = v;
        }
    };

    load_tiles(0);

    for (int k0 = 0; k0 < I_DIM; k0 += BK) {
        // previous tile's MFMA ds_reads complete (own lgkm) + all-wave sync;
        // global prefetch stays in flight (no vmcnt drain).
        asm volatile("s_waitcnt lgkmcnt(0)" ::: "memory");
        __builtin_amdgcn_s_barrier();
        store_tiles();                 // compiler waits vmcnt for ar/br here
        if (k0 + BK < I_DIM) load_tiles(k0 + BK);   // prefetch overlaps MFMA
        asm volatile("s_waitcnt lgkmcnt(0)" ::: "memory");
        __builtin_amdgcn_s_barrier();  // staged tile visible

        #pragma unroll
        for (int kt = 0; kt < 2; ++kt) {
            bf16x8 af[4], bfr[4];
            #pragma unroll
            for (int i = 0; i < 4; ++i)
                af[i] = *(const bf16x8*)(As + (wm + i * 16 + l16) * LDK + kt * 32 + quad * 8);
            #pragma unroll
            for (int i = 0; i < 4; ++i)
                bfr[i] = *(const bf16x8*)(Bs + (wn + i * 16 + l16) * LDK + kt * 32 + quad * 8);
            #pragma unroll
            for (int i = 0; i < 4; ++i)
                #pragma unroll
                for (int j = 0; j < 4; ++j)
                    acc[i][j] = __builtin_amdgcn_mfma_f32_16x16x32_bf16(af[i], bfr[j], acc[i][j], 0, 0, 0);
        }
    }

    // epilogue: C[row][col], col = lane&15, row = quad*4 + reg   (verified m89/m91)
    #pragma unroll
    for (int j = 0; j < 4; ++j) {
        const int col  = wn + j * 16 + l16;
        const float bias = b_ih[col] + b_hh[col];
        #pragma unroll
        for (int i = 0; i < 4; ++i) {
            #pragma unroll
            for (int r = 0; r < 4; ++r) {
                const int row = wm + i * 16 + quad * 4 + r;
                xp[(size_t)(m0 + row) * H_DIM + col] = acc[i][j][r] + bias;
            }
        }
    }
}

// ---------------------------------------------------------------------------
// Kernel 2: per-batch RNN scan + FC1 + FC2 + LayerNorm. 64 blocks x 256 thr.
// Thread t: j = t>>1 (output row), half = t&1 (K-half). W_hh half-row (64
// floats) in regs. 4 waves (vs 8 before): half the barrier skew and half the
// per-step LDS instruction contention. Single DPP xor-1 combines the halves.
// h double-buffered in LDS, chunked [2][2][68]: the two K-half chunks start
// 68 floats apart (offset 4 banks) -> the wave's 2 distinct broadcast
// ds_read_b128 addresses hit disjoint bank groups (conflict-free).
// One raw s_barrier per step with lgkmcnt(0) only (no vmcnt drain).
// ---------------------------------------------------------------------------
#define CH 68   // 64 data floats + 4 pad per chunk

__global__ __launch_bounds__(256) void rnn_tail(
    const float* __restrict__ xp,     // [64, 512, 128]  (bias pre-added)
    const float* __restrict__ Whh,    // [128, 128]
    const float* __restrict__ W1, const float* __restrict__ b1,
    const float* __restrict__ W2, const float* __restrict__ b2,
    const float* __restrict__ gamma, const float* __restrict__ beta,
    float* __restrict__ out)          // [64, 128]
{
    __shared__ float hs[2][2][CH];    // h double buffer, chunked by K-half
    __shared__ float zb[2][CH];       // z1, chunked
    __shared__ float red[4][2];

    const int tid  = threadIdx.x;
    const int b    = blockIdx.x;
    const int j    = tid >> 1;   // output row 0..127
    const int half = tid & 1;    // K-half 0..1

    // W_hh[j][half*64 .. +64) resident in 16 float4 registers
    float4 wr[16];
    {
        const float4* wrow = (const float4*)(Whh + j * H_DIM + half * 64);
        #pragma unroll
        for (int i = 0; i < 16; ++i) wr[i] = wrow[i];
    }

    if (tid < H_DIM) hs[0][tid >> 6][tid & 63] = 0.f;
    const float* xptr = xp + (size_t)b * T_STEPS * H_DIM + j;
    float xv = *xptr;                  // step-0 input (same for both halves)
    __syncthreads();

    #pragma unroll 1
    for (int t = 0; t < T_STEPS - 1; ++t) {
        float xnext = xptr[H_DIM];     // always in-bounds (t+1 <= 511)
        xptr += H_DIM;

        const float4* hv = (const float4*)(hs[t & 1][half]);
        float p0 = 0.f, p1 = 0.f, p2 = 0.f, p3 = 0.f;
        #pragma unroll
        for (int i = 0; i < 16; i += 4) {
            float4 h0 = hv[i], h1 = hv[i + 1], h2 = hv[i + 2], h3 = hv[i + 3];
            p0 += wr[i].x     * h0.x + wr[i].y     * h0.y + wr[i].z     * h0.z + wr[i].w     * h0.w;
            p1 += wr[i + 1].x * h1.x + wr[i + 1].y * h1.y + wr[i + 1].z * h1.z + wr[i + 1].w * h1.w;
            p2 += wr[i + 2].x * h2.x + wr[i + 2].y * h2.y + wr[i + 2].z * h2.z + wr[i + 2].w * h2.w;
            p3 += wr[i + 3].x * h3.x + wr[i + 3].y * h3.y + wr[i + 3].z * h3.z + wr[i + 3].w * h3.w;
        }
        float p = dpp_add_xor1((p0 + p1) + (p2 + p3));   // combine K-halves

        float a  = xv + p;
        float e  = __expf(-2.f * fabsf(a));
        float th = (1.f - e) / (1.f + e);
        th = copysignf(th, a);

        if (half == 0) hs[(t + 1) & 1][j >> 6][j & 63] = th;
        xv = xnext;
        // single barrier per step: LDS writes visible, NO vmcnt drain
        asm volatile("s_waitcnt lgkmcnt(0)" ::: "memory");
        __builtin_amdgcn_s_barrier();
        asm volatile("" ::: "memory");
    }

    // final step t = T_STEPS-1 (no prefetch); reads hs[1], writes hs[0]
    {
        const float4* hv = (const float4*)(hs[(T_STEPS - 1) & 1][half]);
        float p0 = 0.f, p1 = 0.f, p2 = 0.f, p3 = 0.f;
        #pragma unroll
        for (int i = 0; i < 16; i += 4) {
            float4 h0 = hv[i], h1 = hv[i + 1], h2 = hv[i + 2], h3 = hv[i + 3];
            p0 += wr[i].x     * h0.x + wr[i].y     * h0.y + wr[i].z     * h0.z + wr[i].w     * h0.w;
            p1 += wr[i + 1].x * h1.x + wr[i + 1].y * h1.y + wr[i + 1].z * h1.z + wr[i + 1].w * h1.w;
            p2 += wr[i + 2].x * h2.x + wr[i + 2].y * h2.y + wr[i + 2].z * h2.z + wr[i + 2].w * h2.w;
            p3 += wr[i + 3].x * h3.x + wr[i + 3].y * h3.y + wr[i + 3].z * h3.z + wr[i + 3].w * h3.w;
        }
        float p = dpp_add_xor1((p0 + p1) + (p2 + p3));
        float a  = xv + p;
        float e  = __expf(-2.f * fabsf(a));
        float th = (1.f - e) / (1.f + e);
        th = copysignf(th, a);
        if (half == 0) hs[0][j >> 6][j & 63] = th;
        __syncthreads();
    }
    // hT now in hs[0]

    // ---- FC1: z1 = relu(hT @ W1^T + b1) ----
    {
        const float4* wv = (const float4*)(W1 + j * H_DIM + half * 64);
        const float4* hv = (const float4*)(hs[0][half]);
        float p0 = 0.f, p1 = 0.f;
        #pragma unroll
        for (int i = 0; i < 16; i += 2) {
            float4 w0 = wv[i], w1_ = wv[i + 1], h0 = hv[i], h1 = hv[i + 1];
            p0 += w0.x * h0.x + w0.y * h0.y + w0.z * h0.z + w0.w * h0.w;
            p1 += w1_.x * h1.x + w1_.y * h1.y + w1_.z * h1.z + w1_.w * h1.w;
        }
        float p = dpp_add_xor1(p0 + p1);
        float z = fmaxf(p + b1[j], 0.f);
        if (half == 0) zb[j >> 6][j & 63] = z;
    }
    __syncthreads();

    // ---- FC2: z2 = relu(z1 @ W2^T + b2) ----
    {
        const float4* wv = (const float4*)(W2 + j * H_DIM + half * 64);
        const float4* zv = (const float4*)(zb[half]);
        float p0 = 0.f, p1 = 0.f;
        #pragma unroll
        for (int i = 0; i < 16; i += 2) {
            float4 w0 = wv[i], w1_ = wv[i + 1], z0 = zv[i], z1 = zv[i + 1];
            p0 += w0.x * z0.x + w0.y * z0.y + w0.z * z0.z + w0.w * z0.w;
            p1 += w1_.x * z1.x + w1_.y * z1.y + w1_.z * z1.z + w1_.w * z1.w;
        }
        float p = dpp_add_xor1(p0 + p1);
        float z2 = fmaxf(p + b2[j], 0.f);
        if (half == 0) hs[1][j >> 6][j & 63] = z2;   // reuse hs[1] for z2
    }
    __syncthreads();

    // ---- LayerNorm over 128 features ----
    float v = (tid < H_DIM) ? hs[1][tid >> 6][tid & 63] : 0.f;
    float s = v, sq = v * v;
    #pragma unroll
    for (int o = 1; o < 64; o <<= 1) {
        s  += __shfl_xor(s, o);
        sq += __shfl_xor(sq, o);
    }
    const int lane = tid & 63, wave = tid >> 6;
    if (lane == 0) { red[wave][0] = s; red[wave][1] = sq; }
    __syncthreads();
    float S = 0.f, Q = 0.f;
    #pragma unroll
    for (int wv2 = 0; wv2 < 4; ++wv2) { S += red[wv2][0]; Q += red[wv2][1]; }
    float mu   = S * (1.f / 128.f);
    float var  = Q * (1.f / 128.f) - mu * mu;
    float rstd = rsqrtf(var + 1e-5f);
    if (tid < H_DIM)
        out[b * H_DIM + tid] = gamma[tid] * (v - mu) * rstd + beta[tid];
}

// ---------------------------------------------------------------------------
extern "C" void kernel_launch(void* const* d_in, const int* in_sizes, int n_in,
                              void* d_out, int out_size, void* d_ws, size_t ws_size,
                              hipStream_t stream) {
    const float* x     = (const float*)d_in[0];
    const float* W_ih  = (const float*)d_in[1];
    const float* b_ih  = (const float*)d_in[2];
    const float* W_hh  = (const float*)d_in[3];
    const float* b_hh  = (const float*)d_in[4];
    const float* W1    = (const float*)d_in[5];
    const float* b1    = (const float*)d_in[6];
    const float* W2    = (const float*)d_in[7];
    const float* b2    = (const float*)d_in[8];
    const float* gamma = (const float*)d_in[9];
    const float* beta  = (const float*)d_in[10];
    float* out = (float*)d_out;

    float* xp = (float*)d_ws;          // 32768*128*4 = 16 MB scratch

    gemm_xp<<<dim3(M_TOT / BM), dim3(256), 0, stream>>>(x, W_ih, b_ih, b_hh, xp);
    rnn_tail<<<dim3(B_DIM), dim3(256), 0, stream>>>(xp, W_hh, W1, b1, W2, b2,
                                                    gamma, beta, out);
}

// Round 4
// 605.534 us; speedup vs baseline: 1.0495x; 1.0495x over previous
//
#include <hip/hip_runtime.h>

// ---------------------------------------------------------------------------
// Model: xp = x @ W_ih^T + (b_ih + b_hh)   [bf16 MFMA GEMM, fp32 accumulate]
//        h_t = tanh(xp_t + h_{t-1} @ W_hh^T)   [fp32, latency-optimized scan]
//        out = LN(relu(relu(hT W1^T + b1) W2^T + b2))  [fused into RNN tail]
// ---------------------------------------------------------------------------

typedef __bf16 bf16x8 __attribute__((ext_vector_type(8)));
typedef float  f32x4  __attribute__((ext_vector_type(4)));

#define T_STEPS 512
#define I_DIM   2048
#define H_DIM   128
#define B_DIM   64
#define M_TOT   (B_DIM * T_STEPS)   // 32768

// RNE fp32 -> bf16 (inputs are finite; no NaN path needed)
__device__ __forceinline__ unsigned short f2bf(float f) {
    unsigned int u = __float_as_uint(f);
    u += 0x7FFFu + ((u >> 16) & 1u);
    return (unsigned short)(u >> 16);
}

// Sum over each aligned 8-lane group, entirely in the VALU pipe (DPP):
// xor1 (quad_perm [1,0,3,2]), xor2 (quad_perm [2,3,0,1]), then
// row_half_mirror (0x141) which maps lane l -> (l&~7)|(7-(l&7)), crossing
// the two quads of the 8-group. All 8 lanes end with the total.
__device__ __forceinline__ float red8(float x) {
    int t1 = __builtin_amdgcn_update_dpp(0, __float_as_int(x),
                                         0xB1, 0xF, 0xF, true);
    float y = x + __int_as_float(t1);
    int t2 = __builtin_amdgcn_update_dpp(0, __float_as_int(y),
                                         0x4E, 0xF, 0xF, true);
    float z = y + __int_as_float(t2);
    int t3 = __builtin_amdgcn_update_dpp(0, __float_as_int(z),
                                         0x141, 0xF, 0xF, true);
    return z + __int_as_float(t3);
}

// ---------------------------------------------------------------------------
// Kernel 1: xp[M,128] = x[M,2048] (bf16) @ W_ih[128,2048]^T (bf16) + bias
// BM=128, BN=128(=H), BK=64. 256 threads = 4 waves in 2x2, each wave 64x64.
// fp32 -> bf16 conversion fused into LDS staging (x read exactly once).
// Raw s_barrier + lgkmcnt(0) only: k+1 global prefetch never vmcnt-drained.
// ---------------------------------------------------------------------------
#define BM  128
#define BK  64
#define LDK 72   // LDS row stride in bf16 elems (+8 pad -> 2-way-max bank alias)

__global__ __launch_bounds__(256) void gemm_xp(
    const float* __restrict__ x,      // [32768, 2048]
    const float* __restrict__ w,      // [128, 2048]
    const float* __restrict__ b_ih,   // [128]
    const float* __restrict__ b_hh,   // [128]
    float* __restrict__ xp)           // [32768, 128]
{
    __shared__ __align__(16) unsigned short As[BM * LDK];
    __shared__ __align__(16) unsigned short Bs[H_DIM * LDK];

    const int tid = threadIdx.x;
    const int m0  = blockIdx.x * BM;

    const int r0 = tid >> 4;      // 0..15
    const int c4 = tid & 15;      // float4 column within 64-float row chunk

    const int lane = tid & 63;
    const int wave = tid >> 6;
    const int wm   = (wave >> 1) * 64;
    const int wn   = (wave & 1) * 64;
    const int l16  = lane & 15;
    const int quad = lane >> 4;

    f32x4 acc[4][4] = {};

    float4 ar[8], br[8];

    auto load_tiles = [&](int k0) {
        #pragma unroll
        for (int i = 0; i < 8; ++i)
            ar[i] = *(const float4*)(x + (size_t)(m0 + i * 16 + r0) * I_DIM + k0 + c4 * 4);
        #pragma unroll
        for (int i = 0; i < 8; ++i)
            br[i] = *(const float4*)(w + (size_t)(i * 16 + r0) * I_DIM + k0 + c4 * 4);
    };

    auto store_tiles = [&]() {
        #pragma unroll
        for (int i = 0; i < 8; ++i) {
            ushort4 v;
            v.x = f2bf(ar[i].x); v.y = f2bf(ar[i].y);
            v.z = f2bf(ar[i].z); v.w = f2bf(ar[i].w);
            *(ushort4*)(As + (i * 16 + r0) * LDK + c4 * 4) = v;
        }
        #pragma unroll
        for (int i = 0; i < 8; ++i) {
            ushort4 v;
            v.x = f2bf(br[i].x); v.y = f2bf(br[i].y);
            v.z = f2bf(br[i].z); v.w = f2bf(br[i].w);
            *(ushort4*)(Bs + (i * 16 + r0) * LDK + c4 * 4) = v;
        }
    };

    load_tiles(0);

    for (int k0 = 0; k0 < I_DIM; k0 += BK) {
        asm volatile("s_waitcnt lgkmcnt(0)" ::: "memory");
        __builtin_amdgcn_s_barrier();
        store_tiles();                 // compiler waits vmcnt for ar/br here
        if (k0 + BK < I_DIM) load_tiles(k0 + BK);   // prefetch overlaps MFMA
        asm volatile("s_waitcnt lgkmcnt(0)" ::: "memory");
        __builtin_amdgcn_s_barrier();  // staged tile visible

        #pragma unroll
        for (int kt = 0; kt < 2; ++kt) {
            bf16x8 af[4], bfr[4];
            #pragma unroll
            for (int i = 0; i < 4; ++i)
                af[i] = *(const bf16x8*)(As + (wm + i * 16 + l16) * LDK + kt * 32 + quad * 8);
            #pragma unroll
            for (int i = 0; i < 4; ++i)
                bfr[i] = *(const bf16x8*)(Bs + (wn + i * 16 + l16) * LDK + kt * 32 + quad * 8);
            #pragma unroll
            for (int i = 0; i < 4; ++i)
                #pragma unroll
                for (int j = 0; j < 4; ++j)
                    acc[i][j] = __builtin_amdgcn_mfma_f32_16x16x32_bf16(af[i], bfr[j], acc[i][j], 0, 0, 0);
        }
    }

    // epilogue: C[row][col], col = lane&15, row = quad*4 + reg
    #pragma unroll
    for (int j = 0; j < 4; ++j) {
        const int col  = wn + j * 16 + l16;
        const float bias = b_ih[col] + b_hh[col];
        #pragma unroll
        for (int i = 0; i < 4; ++i) {
            #pragma unroll
            for (int r = 0; r < 4; ++r) {
                const int row = wm + i * 16 + quad * 4 + r;
                xp[(size_t)(m0 + row) * H_DIM + col] = acc[i][j][r] + bias;
            }
        }
    }
}

// ---------------------------------------------------------------------------
// Kernel 2: per-batch RNN scan + FC1 + FC2 + LayerNorm. 64 blocks x 512 thr.
// Thread t: jj = t>>3 (row pair jj, jj+64), k = t&7 (K-split of 16 floats).
// Per step each thread does 4 ds_read_b128 (16 h floats) and 32 FMAs for TWO
// output rows -> LDS lane-traffic halved vs the quarter-split (32 wave-instrs
// per step instead of 64); the 8-lane reduce is pure-VALU DPP (red8).
// h chunk layout [8][20]: chunk k at float offset 20k -> the 8 distinct 16B
// segments land on bank offsets {0,20,8,28,16,4,24,12} -> all 32 banks,
// disjoint, conflict-free (16B granules 4 banks apart).
// One raw s_barrier per step with lgkmcnt(0) only (no vmcnt drain).
// ---------------------------------------------------------------------------
#define KCH 20   // 16 data floats + 4 pad per chunk

__global__ __launch_bounds__(512) void rnn_tail(
    const float* __restrict__ xp,     // [64, 512, 128]  (bias pre-added)
    const float* __restrict__ Whh,    // [128, 128]
    const float* __restrict__ W1, const float* __restrict__ b1,
    const float* __restrict__ W2, const float* __restrict__ b2,
    const float* __restrict__ gamma, const float* __restrict__ beta,
    float* __restrict__ out)          // [64, 128]
{
    __shared__ float hs[2][8][KCH];   // h double buffer, chunked by K-split
    __shared__ float zb[8][KCH];      // z1, chunked
    __shared__ float red[8][2];

    const int tid = threadIdx.x;
    const int b   = blockIdx.x;
    const int jj  = tid >> 3;    // row pair: rows jj and jj+64
    const int k   = tid & 7;     // K-split 0..7 (h[16k .. 16k+16))

    // W_hh[jj][16k..+16) and W_hh[jj+64][16k..+16) resident in 8 float4 regs
    float4 wa[4], wb[4];
    {
        const float4* wra = (const float4*)(Whh + jj * H_DIM + k * 16);
        const float4* wrb = (const float4*)(Whh + (jj + 64) * H_DIM + k * 16);
        #pragma unroll
        for (int i = 0; i < 4; ++i) { wa[i] = wra[i]; wb[i] = wrb[i]; }
    }

    // zero h buffers (incl. pads)
    if (tid < 2 * 8 * KCH) ((float*)hs)[tid] = 0.f;
    const float* xpp = xp + (size_t)b * T_STEPS * H_DIM;
    float xv0 = xpp[jj];
    float xv1 = xpp[jj + 64];
    const float* xptr = xpp + H_DIM;   // points at step t+1 row
    __syncthreads();

    #pragma unroll 1
    for (int t = 0; t < T_STEPS - 1; ++t) {
        float xn0 = xptr[jj];          // prefetch t+1 (always in-bounds)
        float xn1 = xptr[jj + 64];
        xptr += H_DIM;

        const float4* hv = (const float4*)(hs[t & 1][k]);
        float4 h0 = hv[0], h1 = hv[1], h2 = hv[2], h3 = hv[3];

        float a0 = wa[0].x * h0.x + wa[0].y * h0.y + wa[0].z * h0.z + wa[0].w * h0.w;
        float a1 = wa[1].x * h1.x + wa[1].y * h1.y + wa[1].z * h1.z + wa[1].w * h1.w;
        float a2 = wa[2].x * h2.x + wa[2].y * h2.y + wa[2].z * h2.z + wa[2].w * h2.w;
        float a3 = wa[3].x * h3.x + wa[3].y * h3.y + wa[3].z * h3.z + wa[3].w * h3.w;
        float c0 = wb[0].x * h0.x + wb[0].y * h0.y + wb[0].z * h0.z + wb[0].w * h0.w;
        float c1 = wb[1].x * h1.x + wb[1].y * h1.y + wb[1].z * h1.z + wb[1].w * h1.w;
        float c2 = wb[2].x * h2.x + wb[2].y * h2.y + wb[2].z * h2.z + wb[2].w * h2.w;
        float c3 = wb[3].x * h3.x + wb[3].y * h3.y + wb[3].z * h3.z + wb[3].w * h3.w;

        float s0 = red8((a0 + a1) + (a2 + a3));
        float s1 = red8((c0 + c1) + (c2 + c3));

        float x0 = xv0 + s0;
        float e0 = __expf(-2.f * fabsf(x0));
        float t0 = copysignf((1.f - e0) / (1.f + e0), x0);
        float x1 = xv1 + s1;
        float e1 = __expf(-2.f * fabsf(x1));
        float t1 = copysignf((1.f - e1) / (1.f + e1), x1);

        if (k == 0) {
            float* hn = (float*)(hs[(t + 1) & 1]);
            hn[(jj >> 4) * KCH + (jj & 15)]       = t0;   // row jj
            hn[(4 + (jj >> 4)) * KCH + (jj & 15)] = t1;   // row jj+64
        }
        xv0 = xn0; xv1 = xn1;
        // single barrier per step: LDS writes visible, NO vmcnt drain
        asm volatile("s_waitcnt lgkmcnt(0)" ::: "memory");
        __builtin_amdgcn_s_barrier();
        asm volatile("" ::: "memory");
    }

    // final step t = T_STEPS-1: reads hs[1], writes hT into hs[0]
    {
        const float4* hv = (const float4*)(hs[1][k]);
        float4 h0 = hv[0], h1 = hv[1], h2 = hv[2], h3 = hv[3];
        float a0 = wa[0].x * h0.x + wa[0].y * h0.y + wa[0].z * h0.z + wa[0].w * h0.w;
        float a1 = wa[1].x * h1.x + wa[1].y * h1.y + wa[1].z * h1.z + wa[1].w * h1.w;
        float a2 = wa[2].x * h2.x + wa[2].y * h2.y + wa[2].z * h2.z + wa[2].w * h2.w;
        float a3 = wa[3].x * h3.x + wa[3].y * h3.y + wa[3].z * h3.z + wa[3].w * h3.w;
        float c0 = wb[0].x * h0.x + wb[0].y * h0.y + wb[0].z * h0.z + wb[0].w * h0.w;
        float c1 = wb[1].x * h1.x + wb[1].y * h1.y + wb[1].z * h1.z + wb[1].w * h1.w;
        float c2 = wb[2].x * h2.x + wb[2].y * h2.y + wb[2].z * h2.z + wb[2].w * h2.w;
        float c3 = wb[3].x * h3.x + wb[3].y * h3.y + wb[3].z * h3.z + wb[3].w * h3.w;
        float s0 = red8((a0 + a1) + (a2 + a3));
        float s1 = red8((c0 + c1) + (c2 + c3));
        float x0 = xv0 + s0;
        float e0 = __expf(-2.f * fabsf(x0));
        float t0 = copysignf((1.f - e0) / (1.f + e0), x0);
        float x1 = xv1 + s1;
        float e1 = __expf(-2.f * fabsf(x1));
        float t1 = copysignf((1.f - e1) / (1.f + e1), x1);
        if (k == 0) {
            float* hn = (float*)(hs[0]);
            hn[(jj >> 4) * KCH + (jj & 15)]       = t0;
            hn[(4 + (jj >> 4)) * KCH + (jj & 15)] = t1;
        }
        __syncthreads();
    }
    // hT in hs[0] (chunked layout)

    // ---- FC1: z1 = relu(hT @ W1^T + b1) ----
    {
        const float4* wva = (const float4*)(W1 + jj * H_DIM + k * 16);
        const float4* wvb = (const float4*)(W1 + (jj + 64) * H_DIM + k * 16);
        const float4* hv  = (const float4*)(hs[0][k]);
        float4 h0 = hv[0], h1 = hv[1], h2 = hv[2], h3 = hv[3];
        float a0 = wva[0].x*h0.x + wva[0].y*h0.y + wva[0].z*h0.z + wva[0].w*h0.w
                 + wva[1].x*h1.x + wva[1].y*h1.y + wva[1].z*h1.z + wva[1].w*h1.w;
        float a1 = wva[2].x*h2.x + wva[2].y*h2.y + wva[2].z*h2.z + wva[2].w*h2.w
                 + wva[3].x*h3.x + wva[3].y*h3.y + wva[3].z*h3.z + wva[3].w*h3.w;
        float c0 = wvb[0].x*h0.x + wvb[0].y*h0.y + wvb[0].z*h0.z + wvb[0].w*h0.w
                 + wvb[1].x*h1.x + wvb[1].y*h1.y + wvb[1].z*h1.z + wvb[1].w*h1.w;
        float c1 = wvb[2].x*h2.x + wvb[2].y*h2.y + wvb[2].z*h2.z + wvb[2].w*h2.w
                 + wvb[3].x*h3.x + wvb[3].y*h3.y + wvb[3].z*h3.z + wvb[3].w*h3.w;
        float s0 = red8(a0 + a1);
        float s1 = red8(c0 + c1);
        float z0 = fmaxf(s0 + b1[jj], 0.f);
        float z1 = fmaxf(s1 + b1[jj + 64], 0.f);
        if (k == 0) {
            zb[jj >> 4][jj & 15]       = z0;
            zb[4 + (jj >> 4)][jj & 15] = z1;
        }
    }
    __syncthreads();

    // ---- FC2: z2 = relu(z1 @ W2^T + b2) ----
    {
        const float4* wva = (const float4*)(W2 + jj * H_DIM + k * 16);
        const float4* wvb = (const float4*)(W2 + (jj + 64) * H_DIM + k * 16);
        const float4* zv  = (const float4*)(zb[k]);
        float4 h0 = zv[0], h1 = zv[1], h2 = zv[2], h3 = zv[3];
        float a0 = wva[0].x*h0.x + wva[0].y*h0.y + wva[0].z*h0.z + wva[0].w*h0.w
                 + wva[1].x*h1.x + wva[1].y*h1.y + wva[1].z*h1.z + wva[1].w*h1.w;
        float a1 = wva[2].x*h2.x + wva[2].y*h2.y + wva[2].z*h2.z + wva[2].w*h2.w
                 + wva[3].x*h3.x + wva[3].y*h3.y + wva[3].z*h3.z + wva[3].w*h3.w;
        float c0 = wvb[0].x*h0.x + wvb[0].y*h0.y + wvb[0].z*h0.z + wvb[0].w*h0.w
                 + wvb[1].x*h1.x + wvb[1].y*h1.y + wvb[1].z*h1.z + wvb[1].w*h1.w;
        float c1 = wvb[2].x*h2.x + wvb[2].y*h2.y + wvb[2].z*h2.z + wvb[2].w*h2.w
                 + wvb[3].x*h3.x + wvb[3].y*h3.y + wvb[3].z*h3.z + wvb[3].w*h3.w;
        float s0 = red8(a0 + a1);
        float s1 = red8(c0 + c1);
        float z0 = fmaxf(s0 + b2[jj], 0.f);
        float z1 = fmaxf(s1 + b2[jj + 64], 0.f);
        if (k == 0) {
            float* hn = (float*)(hs[1]);       // reuse hs[1] for z2
            hn[(jj >> 4) * KCH + (jj & 15)]       = z0;
            hn[(4 + (jj >> 4)) * KCH + (jj & 15)] = z1;
        }
    }
    __syncthreads();

    // ---- LayerNorm over 128 features ----
    float v = 0.f;
    if (tid < H_DIM) v = ((float*)(hs[1]))[(tid >> 4) * KCH + (tid & 15)];
    float s = v, sq = v * v;
    #pragma unroll
    for (int o = 1; o < 64; o <<= 1) {
        s  += __shfl_xor(s, o);
        sq += __shfl_xor(sq, o);
    }
    const int lane = tid & 63, wave = tid >> 6;
    if (lane == 0) { red[wave][0] = s; red[wave][1] = sq; }
    __syncthreads();
    float S = 0.f, Q = 0.f;
    #pragma unroll
    for (int wv2 = 0; wv2 < 8; ++wv2) { S += red[wv2][0]; Q += red[wv2][1]; }
    float mu   = S * (1.f / 128.f);
    float var  = Q * (1.f / 128.f) - mu * mu;
    float rstd = rsqrtf(var + 1e-5f);
    if (tid < H_DIM)
        out[b * H_DIM + tid] = gamma[tid] * (v - mu) * rstd + beta[tid];
}

// ---------------------------------------------------------------------------
extern "C" void kernel_launch(void* const* d_in, const int* in_sizes, int n_in,
                              void* d_out, int out_size, void* d_ws, size_t ws_size,
                              hipStream_t stream) {
    const float* x     = (const float*)d_in[0];
    const float* W_ih  = (const float*)d_in[1];
    const float* b_ih  = (const float*)d_in[2];
    const float* W_hh  = (const float*)d_in[3];
    const float* b_hh  = (const float*)d_in[4];
    const float* W1    = (const float*)d_in[5];
    const float* b1    = (const float*)d_in[6];
    const float* W2    = (const float*)d_in[7];
    const float* b2    = (const float*)d_in[8];
    const float* gamma = (const float*)d_in[9];
    const float* beta  = (const float*)d_in[10];
    float* out = (float*)d_out;

    float* xp = (float*)d_ws;          // 32768*128*4 = 16 MB scratch

    gemm_xp<<<dim3(M_TOT / BM), dim3(256), 0, stream>>>(x, W_ih, b_ih, b_hh, xp);
    rnn_tail<<<dim3(B_DIM), dim3(512), 0, stream>>>(xp, W_hh, W1, b1, W2, b2,
                                                    gamma, beta, out);
}

// Round 5
// 563.639 us; speedup vs baseline: 1.1276x; 1.0743x over previous
//
#include <hip/hip_runtime.h>

// ---------------------------------------------------------------------------
// Model: xp = x @ W_ih^T + (b_ih + b_hh)   [bf16 MFMA GEMM, fp32 accumulate]
//        h_t = tanh(xp_t + h_{t-1} @ W_hh^T)   [fp32, latency-optimized scan]
//        out = LN(relu(relu(hT W1^T + b1) W2^T + b2))  [fused into RNN tail]
// ---------------------------------------------------------------------------

typedef __bf16 bf16x8 __attribute__((ext_vector_type(8)));
typedef float  f32x4  __attribute__((ext_vector_type(4)));

#define T_STEPS 512
#define I_DIM   2048
#define H_DIM   128
#define B_DIM   64
#define M_TOT   (B_DIM * T_STEPS)   // 32768

// packed fp32x2 -> bf16x2 (RNE), native gfx950 instruction
__device__ __forceinline__ unsigned int cvt_pk_bf16(float lo, float hi) {
    unsigned int r;
    asm volatile("v_cvt_pk_bf16_f32 %0, %1, %2" : "=v"(r) : "v"(lo), "v"(hi));
    return r;
}

// fast tanh: th = copysign(1 - 2e/(1+e), a),  e = 2^(-2*log2e*|a|) = e^(-2|a|)
// raw v_exp + raw v_rcp (~1 ulp) — ~4 ops shorter chain than __expf + fdiv.
__device__ __forceinline__ float fast_tanh(float a) {
    float t2 = -2.885390082f * fabsf(a);          // -2*log2(e)*|a|
    float e;
    asm volatile("v_exp_f32 %0, %1" : "=v"(e) : "v"(t2));
    float r;
    asm volatile("v_rcp_f32 %0, %1" : "=v"(r) : "v"(1.f + e));
    return copysignf(1.f - (e + e) * r, a);
}

// Pairwise DPP adds (VALU pipe, no LDS) for the quad-local K-reduction.
__device__ __forceinline__ float quad_sum(float x) {
    int t1 = __builtin_amdgcn_update_dpp(0, __float_as_int(x),
                                         0xB1 /*[1,0,3,2]*/, 0xF, 0xF, true);
    float y = x + __int_as_float(t1);
    int t2 = __builtin_amdgcn_update_dpp(0, __float_as_int(y),
                                         0x4E /*[2,3,0,1]*/, 0xF, 0xF, true);
    return y + __int_as_float(t2);
}

// ---------------------------------------------------------------------------
// Kernel 1: xp[M,128] = x[M,2048] (bf16) @ W_ih[128,2048]^T (bf16) + bias
// BM=128, BN=128(=H), BK=64. 512 threads = 8 waves (2/SIMD for latency
// hiding; previous 256-thr version ran 1 wave/SIMD with zero overlap).
// Wave grid 2x4: each wave computes 64x32 (acc[4][2]).
// fp32->bf16 conversion via v_cvt_pk_bf16_f32 fused into LDS staging.
// Raw s_barrier + lgkmcnt(0) only: k+1 global prefetch never vmcnt-drained.
// ---------------------------------------------------------------------------
#define BM  128
#define BK  64
#define LDK 72   // LDS row stride in bf16 elems (+8 pad -> 2-way-max bank alias)

__global__ __launch_bounds__(512) void gemm_xp(
    const float* __restrict__ x,      // [32768, 2048]
    const float* __restrict__ w,      // [128, 2048]
    const float* __restrict__ b_ih,   // [128]
    const float* __restrict__ b_hh,   // [128]
    float* __restrict__ xp)           // [32768, 128]
{
    __shared__ __align__(16) unsigned short As[BM * LDK];
    __shared__ __align__(16) unsigned short Bs[H_DIM * LDK];

    const int tid = threadIdx.x;
    const int m0  = blockIdx.x * BM;

    // staging map: per unroll step i (0..3), rows i*32 + r0
    const int r0 = tid >> 4;      // 0..31
    const int c4 = tid & 15;      // float4 column within 64-float row chunk

    const int lane = tid & 63;
    const int wave = tid >> 6;    // 0..7
    const int wm   = (wave >> 2) * 64;   // {0, 64}
    const int wn   = (wave & 3) * 32;    // {0, 32, 64, 96}
    const int l16  = lane & 15;
    const int quad = lane >> 4;

    f32x4 acc[4][2] = {};

    float4 ar[4], br[4];

    auto load_tiles = [&](int k0) {
        #pragma unroll
        for (int i = 0; i < 4; ++i)
            ar[i] = *(const float4*)(x + (size_t)(m0 + i * 32 + r0) * I_DIM + k0 + c4 * 4);
        #pragma unroll
        for (int i = 0; i < 4; ++i)
            br[i] = *(const float4*)(w + (size_t)(i * 32 + r0) * I_DIM + k0 + c4 * 4);
    };

    auto store_tiles = [&]() {
        #pragma unroll
        for (int i = 0; i < 4; ++i) {
            uint2 v;
            v.x = cvt_pk_bf16(ar[i].x, ar[i].y);
            v.y = cvt_pk_bf16(ar[i].z, ar[i].w);
            *(uint2*)(As + (i * 32 + r0) * LDK + c4 * 4) = v;
        }
        #pragma unroll
        for (int i = 0; i < 4; ++i) {
            uint2 v;
            v.x = cvt_pk_bf16(br[i].x, br[i].y);
            v.y = cvt_pk_bf16(br[i].z, br[i].w);
            *(uint2*)(Bs + (i * 32 + r0) * LDK + c4 * 4) = v;
        }
    };

    load_tiles(0);

    for (int k0 = 0; k0 < I_DIM; k0 += BK) {
        asm volatile("s_waitcnt lgkmcnt(0)" ::: "memory");
        __builtin_amdgcn_s_barrier();  // previous tile's MFMA reads done
        store_tiles();                 // compiler waits vmcnt for ar/br here
        if (k0 + BK < I_DIM) load_tiles(k0 + BK);   // prefetch overlaps MFMA
        asm volatile("s_waitcnt lgkmcnt(0)" ::: "memory");
        __builtin_amdgcn_s_barrier();  // staged tile visible

        #pragma unroll
        for (int kt = 0; kt < 2; ++kt) {
            bf16x8 af[4], bfr[2];
            #pragma unroll
            for (int i = 0; i < 4; ++i)
                af[i] = *(const bf16x8*)(As + (wm + i * 16 + l16) * LDK + kt * 32 + quad * 8);
            #pragma unroll
            for (int j = 0; j < 2; ++j)
                bfr[j] = *(const bf16x8*)(Bs + (wn + j * 16 + l16) * LDK + kt * 32 + quad * 8);
            #pragma unroll
            for (int i = 0; i < 4; ++i)
                #pragma unroll
                for (int j = 0; j < 2; ++j)
                    acc[i][j] = __builtin_amdgcn_mfma_f32_16x16x32_bf16(af[i], bfr[j], acc[i][j], 0, 0, 0);
        }
    }

    // epilogue: C[row][col], col = lane&15, row = quad*4 + reg
    #pragma unroll
    for (int j = 0; j < 2; ++j) {
        const int col  = wn + j * 16 + l16;
        const float bias = b_ih[col] + b_hh[col];
        #pragma unroll
        for (int i = 0; i < 4; ++i) {
            #pragma unroll
            for (int r = 0; r < 4; ++r) {
                const int row = wm + i * 16 + quad * 4 + r;
                xp[(size_t)(m0 + row) * H_DIM + col] = acc[i][j][r] + bias;
            }
        }
    }
}

// ---------------------------------------------------------------------------
// Kernel 2: per-batch RNN scan + FC1 + FC2 + LayerNorm. 64 blocks x 512 thr.
// Round-2 structure (best measured: 191.5 us): j = tid>>2 (row), q = tid&3
// (K-quarter, 32 floats). W_hh quarter-row in regs. h double-buffered in LDS,
// chunked [2][4][36] (conflict-free broadcast reads). Quad reduce via DPP.
// One raw s_barrier per step with lgkmcnt(0) only (no vmcnt drain).
// Only new thing vs round 2: fast_tanh (raw v_exp + v_rcp, shorter chain).
// ---------------------------------------------------------------------------
#define CH_PAD 36   // 32 data floats + 4 pad per chunk

__global__ __launch_bounds__(512) void rnn_tail(
    const float* __restrict__ xp,     // [64, 512, 128]  (bias pre-added)
    const float* __restrict__ Whh,    // [128, 128]
    const float* __restrict__ W1, const float* __restrict__ b1,
    const float* __restrict__ W2, const float* __restrict__ b2,
    const float* __restrict__ gamma, const float* __restrict__ beta,
    float* __restrict__ out)          // [64, 128]
{
    __shared__ float hs[2][4][CH_PAD];   // h double buffer, chunked by K-quarter
    __shared__ float zb[4][CH_PAD];      // z1, chunked
    __shared__ float red[8][2];

    const int tid = threadIdx.x;
    const int b   = blockIdx.x;
    const int j   = tid >> 2;    // output row 0..127
    const int q   = tid & 3;     // K-quarter 0..3

    // W_hh[j][q*32 .. +32) resident in 8 float4 registers
    float4 wr[8];
    {
        const float4* wrow = (const float4*)(Whh + j * H_DIM + q * 32);
        #pragma unroll
        for (int i = 0; i < 8; ++i) wr[i] = wrow[i];
    }

    if (tid < H_DIM) hs[0][tid >> 5][tid & 31] = 0.f;
    const float* xptr = xp + (size_t)b * T_STEPS * H_DIM + j;
    float xv = *xptr;                  // step-0 input (same for all 4 quarters)
    __syncthreads();

    #pragma unroll 1
    for (int t = 0; t < T_STEPS - 1; ++t) {
        float xnext = xptr[H_DIM];     // always in-bounds (t+1 <= 511)
        xptr += H_DIM;

        const float4* hv = (const float4*)(hs[t & 1][q]);
        float p0 = 0.f, p1 = 0.f, p2 = 0.f, p3 = 0.f;
        #pragma unroll
        for (int i = 0; i < 8; i += 4) {
            float4 h0 = hv[i], h1 = hv[i + 1], h2 = hv[i + 2], h3 = hv[i + 3];
            p0 += wr[i].x     * h0.x + wr[i].y     * h0.y + wr[i].z     * h0.z + wr[i].w     * h0.w;
            p1 += wr[i + 1].x * h1.x + wr[i + 1].y * h1.y + wr[i + 1].z * h1.z + wr[i + 1].w * h1.w;
            p2 += wr[i + 2].x * h2.x + wr[i + 2].y * h2.y + wr[i + 2].z * h2.z + wr[i + 2].w * h2.w;
            p3 += wr[i + 3].x * h3.x + wr[i + 3].y * h3.y + wr[i + 3].z * h3.z + wr[i + 3].w * h3.w;
        }
        float p = quad_sum((p0 + p1) + (p2 + p3));   // combine K-quarters

        float th = fast_tanh(xv + p);

        if (q == 0) hs[(t + 1) & 1][j >> 5][j & 31] = th;
        xv = xnext;
        // single barrier per step: LDS writes visible, NO vmcnt drain
        asm volatile("s_waitcnt lgkmcnt(0)" ::: "memory");
        __builtin_amdgcn_s_barrier();
        asm volatile("" ::: "memory");
    }

    // final step t = T_STEPS-1 (no prefetch); reads hs[1], writes hs[0]
    {
        const float4* hv = (const float4*)(hs[(T_STEPS - 1) & 1][q]);
        float p0 = 0.f, p1 = 0.f, p2 = 0.f, p3 = 0.f;
        #pragma unroll
        for (int i = 0; i < 8; i += 4) {
            float4 h0 = hv[i], h1 = hv[i + 1], h2 = hv[i + 2], h3 = hv[i + 3];
            p0 += wr[i].x     * h0.x + wr[i].y     * h0.y + wr[i].z     * h0.z + wr[i].w     * h0.w;
            p1 += wr[i + 1].x * h1.x + wr[i + 1].y * h1.y + wr[i + 1].z * h1.z + wr[i + 1].w * h1.w;
            p2 += wr[i + 2].x * h2.x + wr[i + 2].y * h2.y + wr[i + 2].z * h2.z + wr[i + 2].w * h2.w;
            p3 += wr[i + 3].x * h3.x + wr[i + 3].y * h3.y + wr[i + 3].z * h3.z + wr[i + 3].w * h3.w;
        }
        float p  = quad_sum((p0 + p1) + (p2 + p3));
        float th = fast_tanh(xv + p);
        if (q == 0) hs[0][j >> 5][j & 31] = th;
        __syncthreads();
    }
    // hT now in hs[0]

    // ---- FC1: z1 = relu(hT @ W1^T + b1) ----
    {
        const float4* wv = (const float4*)(W1 + j * H_DIM + q * 32);
        const float4* hv = (const float4*)(hs[0][q]);
        float p0 = 0.f, p1 = 0.f;
        #pragma unroll
        for (int i = 0; i < 8; i += 2) {
            float4 w0 = wv[i], w1_ = wv[i + 1], h0 = hv[i], h1 = hv[i + 1];
            p0 += w0.x * h0.x + w0.y * h0.y + w0.z * h0.z + w0.w * h0.w;
            p1 += w1_.x * h1.x + w1_.y * h1.y + w1_.z * h1.z + w1_.w * h1.w;
        }
        float p = quad_sum(p0 + p1);
        float z = fmaxf(p + b1[j], 0.f);
        if (q == 0) zb[j >> 5][j & 31] = z;
    }
    __syncthreads();

    // ---- FC2: z2 = relu(z1 @ W2^T + b2) ----
    {
        const float4* wv = (const float4*)(W2 + j * H_DIM + q * 32);
        const float4* zv = (const float4*)(zb[q]);
        float p0 = 0.f, p1 = 0.f;
        #pragma unroll
        for (int i = 0; i < 8; i += 2) {
            float4 w0 = wv[i], w1_ = wv[i + 1], z0 = zv[i], z1 = zv[i + 1];
            p0 += w0.x * z0.x + w0.y * z0.y + w0.z * z0.z + w0.w * z0.w;
            p1 += w1_.x * z1.x + w1_.y * z1.y + w1_.z * z1.z + w1_.w * z1.w;
        }
        float p = quad_sum(p0 + p1);
        float z2 = fmaxf(p + b2[j], 0.f);
        if (q == 0) hs[1][j >> 5][j & 31] = z2;   // reuse hs[1] for z2
    }
    __syncthreads();

    // ---- LayerNorm over 128 features ----
    float v = (tid < H_DIM) ? hs[1][tid >> 5][tid & 31] : 0.f;
    float s = v, sq = v * v;
    #pragma unroll
    for (int o = 1; o < 64; o <<= 1) {
        s  += __shfl_xor(s, o);
        sq += __shfl_xor(sq, o);
    }
    const int lane = tid & 63, wave = tid >> 6;
    if (lane == 0) { red[wave][0] = s; red[wave][1] = sq; }
    __syncthreads();
    float S = 0.f, Q = 0.f;
    #pragma unroll
    for (int wv2 = 0; wv2 < 8; ++wv2) { S += red[wv2][0]; Q += red[wv2][1]; }
    float mu   = S * (1.f / 128.f);
    float var  = Q * (1.f / 128.f) - mu * mu;
    float rstd = rsqrtf(var + 1e-5f);
    if (tid < H_DIM)
        out[b * H_DIM + tid] = gamma[tid] * (v - mu) * rstd + beta[tid];
}

// ---------------------------------------------------------------------------
extern "C" void kernel_launch(void* const* d_in, const int* in_sizes, int n_in,
                              void* d_out, int out_size, void* d_ws, size_t ws_size,
                              hipStream_t stream) {
    const float* x     = (const float*)d_in[0];
    const float* W_ih  = (const float*)d_in[1];
    const float* b_ih  = (const float*)d_in[2];
    const float* W_hh  = (const float*)d_in[3];
    const float* b_hh  = (const float*)d_in[4];
    const float* W1    = (const float*)d_in[5];
    const float* b1    = (const float*)d_in[6];
    const float* W2    = (const float*)d_in[7];
    const float* b2    = (const float*)d_in[8];
    const float* gamma = (const float*)d_in[9];
    const float* beta  = (const float*)d_in[10];
    float* out = (float*)d_out;

    float* xp = (float*)d_ws;          // 32768*128*4 = 16 MB scratch

    gemm_xp<<<dim3(M_TOT / BM), dim3(512), 0, stream>>>(x, W_ih, b_ih, b_hh, xp);
    rnn_tail<<<dim3(B_DIM), dim3(512), 0, stream>>>(xp, W_hh, W1, b1, W2, b2,
                                                    gamma, beta, out);
}